// Round 1
// baseline (584.947 us; speedup 1.0000x reference)
//
#include <hip/hip_runtime.h>
#include <math.h>

#define N_TOK 131072
#define DIM   64
#define QS    8
#define KS    1024

typedef _Float16 f16x8 __attribute__((ext_vector_type(8)));
typedef float    f32x4 __attribute__((ext_vector_type(4)));

#define RSCALE   2048.0f
#define RISCALE  4.8828125e-4f   // 2^-11

// split fp32 v into f16 limbs + scaled-hi: v ~= hi + lo*2^-11 ; hs = 2048*hi (exact)
#define SPLIT3(v, hi, lo, hs) { _Float16 _h = (_Float16)(v); (hi) = _h;        \
                                (lo) = (_Float16)(((v) - (float)_h) * RSCALE); \
                                (hs) = (_Float16)((float)_h * RSCALE); }

// ---- pre-pass 1: codebook -> f16 limbs in MFMA fragment order (A and B layouts
// share the [idx=lane&15][k=quad*8+j] lane mapping, so F serves as A-frags too).
// F[slot][lane][j], slot = ((q*64+g)*2+l)*2+h  (g: 16-cw group, l: limb, h: K-half)
__global__ void conv_kernel(const float* __restrict__ cb, _Float16* __restrict__ F) {
    int t = blockIdx.x * blockDim.x + threadIdx.x;
    if (t >= 2048 * 64) return;
    const int lane = t & 63, slot = t >> 6;
    const int h = slot & 1, l = (slot >> 1) & 1, g = (slot >> 2) & 63, q = slot >> 8;
    const int cw = g * 16 + (lane & 15);
    const int d0 = h * 32 + (lane >> 4) * 8;
    const float* src = cb + ((size_t)q * KS + cw) * DIM + d0;
    f16x8 v;
#pragma unroll
    for (int j = 0; j < 8; ++j) {
        float c = src[j];
        _Float16 hi = (_Float16)c;
        v[j] = (l == 0) ? hi : (_Float16)((c - (float)hi) * RSCALE);
    }
    *(f16x8*)(F + (size_t)slot * 512 + lane * 8) = v;
}

// ---- pre-pass 2: 2048 * (-||c||^2 / 2) = -1024*||c||^2, seeds the MFMA chain ----
__global__ void dc2_kernel(const float* __restrict__ cb, float* __restrict__ dc2s) {
    int i = blockIdx.x * blockDim.x + threadIdx.x;
    if (i < QS * KS) {
        const float* c = cb + (size_t)i * DIM;
        float s = 0.f;
#pragma unroll
        for (int d = 0; d < DIM; ++d) s = fmaf(c[d], c[d], s);
        dc2s[i] = -1024.0f * s;
    }
}

// ---- main: transposed MFMA (A = codewords, B = token limbs).
// NEW vs previous version: the F fragment stream is staged cooperatively into
// LDS (double-buffered 16KB chunks = 4 groups) via global_load_lds, so the 4
// waves of a block fetch each codeword fragment from L2 ONCE instead of 4x.
// Fragment reads become ds_read_b128 (consecutive 16B/lane, conflict-free).
// F's linear layout matches global_load_lds' wave-uniform-base + lane*16 rule.
#define CHUNK_BYTES 16384          // 4 groups * 4KB
#define CHUNK_HALF  8192           // _Float16 elements per chunk

__global__ __launch_bounds__(256, 4)
void rvq_mfma_kernel(const float* __restrict__ x,
                     const float* __restrict__ cbf,
                     const _Float16* __restrict__ F,
                     const float* __restrict__ dc2s,
                     float* __restrict__ out) {
    __shared__ __attribute__((aligned(16))) _Float16 smem[2 * CHUNK_HALF]; // 32 KB

    const int tid  = threadIdx.x;
    const int wave = tid >> 6;
    const int lane = tid & 63;
    const int quad = lane >> 4;
    const int m    = lane & 15;
    const int quad4 = quad * 4;

    const int tokenBase = blockIdx.x * 128 + wave * 32;
    const int tokA = tokenBase + m, tokB = tokenBase + 16 + m;

    // token limbs (B-frag layout): th = hi, tl = 2048*(r-hi), ts = 2048*hi
    f16x8 thA0, thA1, tlA0, tlA1, tsA0, tsA1;
    f16x8 thB0, thB1, tlB0, tlB1, tsB0, tsB1;
    {
        const float* xa = x + (size_t)tokA * DIM + quad * 8;
        const float* xb = x + (size_t)tokB * DIM + quad * 8;
        f32x4 a0 = __builtin_nontemporal_load((const f32x4*)(xa));
        f32x4 a1 = __builtin_nontemporal_load((const f32x4*)(xa + 4));
        f32x4 a2 = __builtin_nontemporal_load((const f32x4*)(xa + 32));
        f32x4 a3 = __builtin_nontemporal_load((const f32x4*)(xa + 36));
        f32x4 b0 = __builtin_nontemporal_load((const f32x4*)(xb));
        f32x4 b1 = __builtin_nontemporal_load((const f32x4*)(xb + 4));
        f32x4 b2 = __builtin_nontemporal_load((const f32x4*)(xb + 32));
        f32x4 b3 = __builtin_nontemporal_load((const f32x4*)(xb + 36));
#pragma unroll
        for (int j = 0; j < 4; ++j) {
            SPLIT3(a0[j], thA0[j],   tlA0[j],   tsA0[j]);
            SPLIT3(a1[j], thA0[j+4], tlA0[j+4], tsA0[j+4]);
            SPLIT3(a2[j], thA1[j],   tlA1[j],   tsA1[j]);
            SPLIT3(a3[j], thA1[j+4], tlA1[j+4], tsA1[j+4]);
            SPLIT3(b0[j], thB0[j],   tlB0[j],   tsB0[j]);
            SPLIT3(b1[j], thB0[j+4], tlB0[j+4], tsB0[j+4]);
            SPLIT3(b2[j], thB1[j],   tlB1[j],   tsB1[j]);
            SPLIT3(b3[j], thB1[j+4], tlB1[j+4], tsB1[j+4]);
        }
    }

// stage one 16KB chunk (4 groups) of F into LDS buffer BUF.
// dest = wave-uniform base (+ lane*16 implicit); global src is per-lane.
#define STAGE(GC, BUF) {                                                          \
        const char* _gs = (const char*)F + (size_t)(GC) * CHUNK_BYTES             \
                          + (wave << 10) + (lane << 4);                           \
        _Float16* _ld = smem + (BUF) * CHUNK_HALF + (wave << 9);                  \
        _Pragma("unroll")                                                         \
        for (int _j = 0; _j < 4; ++_j)                                            \
            __builtin_amdgcn_global_load_lds(                                     \
                (const __attribute__((address_space(1))) void*)(_gs + _j * 4096), \
                (__attribute__((address_space(3))) void*)(_ld + _j * 2048),       \
                16, 0, 0);                                                        \
    }

// One group: 2 chains of 6 MFMA; acc IS the scaled score, no VALU combine.
#define COMPUTE(CH0, CH1, CL0, CL1, CIV, G) {                                       \
        f32x4 accA = __builtin_amdgcn_mfma_f32_16x16x32_f16(CH0, tsA0, CIV, 0,0,0); \
        f32x4 accB = __builtin_amdgcn_mfma_f32_16x16x32_f16(CH0, tsB0, CIV, 0,0,0); \
        accA = __builtin_amdgcn_mfma_f32_16x16x32_f16(CH1, tsA1, accA, 0,0,0);      \
        accB = __builtin_amdgcn_mfma_f32_16x16x32_f16(CH1, tsB1, accB, 0,0,0);      \
        accA = __builtin_amdgcn_mfma_f32_16x16x32_f16(CL0, thA0, accA, 0,0,0);      \
        accB = __builtin_amdgcn_mfma_f32_16x16x32_f16(CL0, thB0, accB, 0,0,0);      \
        accA = __builtin_amdgcn_mfma_f32_16x16x32_f16(CL1, thA1, accA, 0,0,0);      \
        accB = __builtin_amdgcn_mfma_f32_16x16x32_f16(CL1, thB1, accB, 0,0,0);      \
        accA = __builtin_amdgcn_mfma_f32_16x16x32_f16(CH0, tlA0, accA, 0,0,0);      \
        accB = __builtin_amdgcn_mfma_f32_16x16x32_f16(CH0, tlB0, accB, 0,0,0);      \
        accA = __builtin_amdgcn_mfma_f32_16x16x32_f16(CH1, tlA1, accA, 0,0,0);      \
        accB = __builtin_amdgcn_mfma_f32_16x16x32_f16(CH1, tlB1, accB, 0,0,0);      \
        const int base = (G) * 16 + quad4;                                          \
        _Pragma("unroll")                                                           \
        for (int i = 0; i < 4; ++i) {                                               \
            if (accA[i] > bvA) { bvA = accA[i]; biA = base + i; }                   \
            if (accB[i] > bvB) { bvB = accB[i]; biB = base + i; }                   \
        }                                                                           \
    }

    // prologue: stage chunk 0 of stage 0
    STAGE(0, 0);
    __syncthreads();
    int cur = 0;

    for (int q = 0; q < QS; ++q) {
        const float* dq  = dc2s + q * KS;
        const float* cfq = cbf  + (size_t)q * KS * DIM;

        float bvA = -INFINITY, bvB = -INFINITY;
        int   biA = 0,         biB = 0;

        for (int ch = 0; ch < 16; ++ch) {
            const int gc = (q << 4) | ch;
            if (gc + 1 < 128) STAGE(gc + 1, cur ^ 1);   // prefetch next chunk

            const _Float16* L  = smem + cur * CHUNK_HALF + lane * 8;
            const float*    dg = dq + ch * 64 + quad4;
            const int gbase = ch * 4;

            // register double-buffer over the chunk's 4 groups (ds_read_b128)
            f16x8 c0h0 = *(const f16x8*)(L);
            f16x8 c0h1 = *(const f16x8*)(L + 512);
            f16x8 c0l0 = *(const f16x8*)(L + 1024);
            f16x8 c0l1 = *(const f16x8*)(L + 1536);
            f32x4 ci0  = *(const f32x4*)(dg);

            f16x8 c1h0 = *(const f16x8*)(L + 2048);
            f16x8 c1h1 = *(const f16x8*)(L + 2560);
            f16x8 c1l0 = *(const f16x8*)(L + 3072);
            f16x8 c1l1 = *(const f16x8*)(L + 3584);
            f32x4 ci1  = *(const f32x4*)(dg + 16);

            COMPUTE(c0h0, c0h1, c0l0, c0l1, ci0, gbase + 0);

            c0h0 = *(const f16x8*)(L + 4096);
            c0h1 = *(const f16x8*)(L + 4608);
            c0l0 = *(const f16x8*)(L + 5120);
            c0l1 = *(const f16x8*)(L + 5632);
            ci0  = *(const f32x4*)(dg + 32);

            COMPUTE(c1h0, c1h1, c1l0, c1l1, ci1, gbase + 1);

            c1h0 = *(const f16x8*)(L + 6144);
            c1h1 = *(const f16x8*)(L + 6656);
            c1l0 = *(const f16x8*)(L + 7168);
            c1l1 = *(const f16x8*)(L + 7680);
            ci1  = *(const f32x4*)(dg + 48);

            COMPUTE(c0h0, c0h1, c0l0, c0l1, ci0, gbase + 2);
            COMPUTE(c1h0, c1h1, c1l0, c1l1, ci1, gbase + 3);

            // barrier doubles as vmcnt(0)/lgkmcnt(0) drain: staged chunk gc+1 is
            // now resident+visible, and all waves are done reading buffer cur.
            __syncthreads();
            cur ^= 1;
        }

        // reduce over the 4 quad-lanes holding the same token (disjoint codewords):
        // 2 shuffle steps. Tie-break: lowest index, matching jnp.argmin.
#pragma unroll
        for (int mask = 16; mask <= 32; mask <<= 1) {
            float ovA = __shfl_xor(bvA, mask, 64);
            int   oiA = __shfl_xor(biA, mask, 64);
            if (ovA > bvA || (ovA == bvA && oiA < biA)) { bvA = ovA; biA = oiA; }
            float ovB = __shfl_xor(bvB, mask, 64);
            int   oiB = __shfl_xor(biB, mask, 64);
            if (ovB > bvB || (ovB == bvB && oiB < biB)) { bvB = ovB; biB = oiB; }
        }

        // indices straight to global (every lane already has its token's winner)
        if (quad == 0)      out[(size_t)N_TOK * DIM + (size_t)tokA * QS + q] = (float)biA;
        else if (quad == 1) out[(size_t)N_TOK * DIM + (size_t)tokB * QS + q] = (float)biB;

        // residual update: reconstruct r from limbs, subtract fp32 codeword, re-split
        float ls = 0.f;
        {
            const float* cp = cfq + (size_t)biA * DIM + quad * 8;
            f32x4 c0 = *(const f32x4*)(cp);
            f32x4 c1 = *(const f32x4*)(cp + 4);
            f32x4 c2 = *(const f32x4*)(cp + 32);
            f32x4 c3 = *(const f32x4*)(cp + 36);
#pragma unroll
            for (int j = 0; j < 4; ++j) {
                float v0 = fmaf(RISCALE, (float)tlA0[j],   (float)thA0[j])   - c0[j];
                float v1 = fmaf(RISCALE, (float)tlA0[j+4], (float)thA0[j+4]) - c1[j];
                float v2 = fmaf(RISCALE, (float)tlA1[j],   (float)thA1[j])   - c2[j];
                float v3 = fmaf(RISCALE, (float)tlA1[j+4], (float)thA1[j+4]) - c3[j];
                ls = fmaf(v0, v0, ls); ls = fmaf(v1, v1, ls);
                ls = fmaf(v2, v2, ls); ls = fmaf(v3, v3, ls);
                SPLIT3(v0, thA0[j],   tlA0[j],   tsA0[j]);
                SPLIT3(v1, thA0[j+4], tlA0[j+4], tsA0[j+4]);
                SPLIT3(v2, thA1[j],   tlA1[j],   tsA1[j]);
                SPLIT3(v3, thA1[j+4], tlA1[j+4], tsA1[j+4]);
            }
        }
        {
            const float* cp = cfq + (size_t)biB * DIM + quad * 8;
            f32x4 c0 = *(const f32x4*)(cp);
            f32x4 c1 = *(const f32x4*)(cp + 4);
            f32x4 c2 = *(const f32x4*)(cp + 32);
            f32x4 c3 = *(const f32x4*)(cp + 36);
#pragma unroll
            for (int j = 0; j < 4; ++j) {
                float v0 = fmaf(RISCALE, (float)tlB0[j],   (float)thB0[j])   - c0[j];
                float v1 = fmaf(RISCALE, (float)tlB0[j+4], (float)thB0[j+4]) - c1[j];
                float v2 = fmaf(RISCALE, (float)tlB1[j],   (float)thB1[j])   - c2[j];
                float v3 = fmaf(RISCALE, (float)tlB1[j+4], (float)thB1[j+4]) - c3[j];
                ls = fmaf(v0, v0, ls); ls = fmaf(v1, v1, ls);
                ls = fmaf(v2, v2, ls); ls = fmaf(v3, v3, ls);
                SPLIT3(v0, thB0[j],   tlB0[j],   tsB0[j]);
                SPLIT3(v1, thB0[j+4], tlB0[j+4], tsB0[j+4]);
                SPLIT3(v2, thB1[j],   tlB1[j],   tsB1[j]);
                SPLIT3(v3, thB1[j+4], tlB1[j+4], tsB1[j+4]);
            }
        }
#pragma unroll
        for (int mask = 1; mask <= 32; mask <<= 1) ls += __shfl_xor(ls, mask, 64);
        if (lane == 0)
            atomicAdd(out + (size_t)N_TOK * DIM + (size_t)N_TOK * QS + q,
                      ls * (1.0f / ((float)N_TOK * (float)DIM)));
    }

    // xq = x - r_final (reconstruct final residual from limbs)
    {
        const size_t ra = (size_t)tokA * DIM + quad * 8;
        const size_t rb = (size_t)tokB * DIM + quad * 8;
        f32x4 a0 = __builtin_nontemporal_load((const f32x4*)(x + ra));
        f32x4 a1 = __builtin_nontemporal_load((const f32x4*)(x + ra + 4));
        f32x4 a2 = __builtin_nontemporal_load((const f32x4*)(x + ra + 32));
        f32x4 a3 = __builtin_nontemporal_load((const f32x4*)(x + ra + 36));
        f32x4 b0 = __builtin_nontemporal_load((const f32x4*)(x + rb));
        f32x4 b1 = __builtin_nontemporal_load((const f32x4*)(x + rb + 4));
        f32x4 b2 = __builtin_nontemporal_load((const f32x4*)(x + rb + 32));
        f32x4 b3 = __builtin_nontemporal_load((const f32x4*)(x + rb + 36));
#pragma unroll
        for (int j = 0; j < 4; ++j) {
            a0[j] -= fmaf(RISCALE, (float)tlA0[j],   (float)thA0[j]);
            a1[j] -= fmaf(RISCALE, (float)tlA0[j+4], (float)thA0[j+4]);
            a2[j] -= fmaf(RISCALE, (float)tlA1[j],   (float)thA1[j]);
            a3[j] -= fmaf(RISCALE, (float)tlA1[j+4], (float)thA1[j+4]);
            b0[j] -= fmaf(RISCALE, (float)tlB0[j],   (float)thB0[j]);
            b1[j] -= fmaf(RISCALE, (float)tlB0[j+4], (float)thB0[j+4]);
            b2[j] -= fmaf(RISCALE, (float)tlB1[j],   (float)thB1[j]);
            b3[j] -= fmaf(RISCALE, (float)tlB1[j+4], (float)thB1[j+4]);
        }
        __builtin_nontemporal_store(a0, (f32x4*)(out + ra));
        __builtin_nontemporal_store(a1, (f32x4*)(out + ra + 4));
        __builtin_nontemporal_store(a2, (f32x4*)(out + ra + 32));
        __builtin_nontemporal_store(a3, (f32x4*)(out + ra + 36));
        __builtin_nontemporal_store(b0, (f32x4*)(out + rb));
        __builtin_nontemporal_store(b1, (f32x4*)(out + rb + 4));
        __builtin_nontemporal_store(b2, (f32x4*)(out + rb + 32));
        __builtin_nontemporal_store(b3, (f32x4*)(out + rb + 36));
    }
#undef COMPUTE
#undef STAGE
}

extern "C" void kernel_launch(void* const* d_in, const int* in_sizes, int n_in,
                              void* d_out, int out_size, void* d_ws, size_t ws_size,
                              hipStream_t stream) {
    const float* x   = (const float*)d_in[0];   // (N, D)
    const float* cb  = (const float*)d_in[1];   // (Q, K, D)
    float*       out = (float*)d_out;           // [xq | indices | losses]
    char*        ws  = (char*)d_ws;

    _Float16* F    = (_Float16*)ws;                       // 2 MB fragment-ordered limbs
    float*    dc2s = (float*)(ws + 2097152);              // 32 KB

    hipMemsetAsync(out + (size_t)N_TOK * DIM + (size_t)N_TOK * QS, 0,
                   QS * sizeof(float), stream);

    conv_kernel<<<512, 256, 0, stream>>>(cb, F);
    dc2_kernel<<<(QS * KS + 255) / 256, 256, 0, stream>>>(cb, dc2s);
    rvq_mfma_kernel<<<N_TOK / 128, 256, 0, stream>>>(x, cb, F, dc2s, out);
}

// Round 2
// 579.756 us; speedup vs baseline: 1.0090x; 1.0090x over previous
//
#include <hip/hip_runtime.h>
#include <math.h>

#define N_TOK 131072
#define DIM   64
#define QS    8
#define KS    1024

typedef _Float16 f16x8 __attribute__((ext_vector_type(8)));
typedef float    f32x4 __attribute__((ext_vector_type(4)));

#define RSCALE   2048.0f
#define RISCALE  4.8828125e-4f   // 2^-11

// split fp32 v into f16 limbs + scaled-hi: v ~= hi + lo*2^-11 ; hs = 2048*hi (exact)
#define SPLIT3(v, hi, lo, hs) { _Float16 _h = (_Float16)(v); (hi) = _h;        \
                                (lo) = (_Float16)(((v) - (float)_h) * RSCALE); \
                                (hs) = (_Float16)((float)_h * RSCALE); }

// ---- workspace layout G: 128 chunks, each 16640 B:
//   [0    .. 16383]  frag limbs: 16 sub-slots of 1KB (4 groups x {h0,h1,l0,l1})
//   [16384.. 16639]  64 floats: -1024*||c||^2 seeds for the chunk's 64 codewords
// Chunk c covers stage q = c>>4, codewords (c&15)*64 .. +63.
// Main loop stages a whole chunk with global_load_lds only -> zero non-staging
// vmem in the hot loop (vmcnt FIFO no longer serializes compute on staging).

// ---- pre-pass 1: codebook -> f16 limbs in MFMA fragment order.
// slot = (q*64+g)*4 + l*2 + h ; chunk c = slot>>4, sub = slot&15.
__global__ void conv_kernel(const float* __restrict__ cb, _Float16* __restrict__ G) {
    int t = blockIdx.x * blockDim.x + threadIdx.x;
    if (t >= 2048 * 64) return;
    const int lane = t & 63, slot = t >> 6;
    const int h = slot & 1, l = (slot >> 1) & 1, g = (slot >> 2) & 63, q = slot >> 8;
    const int cw = g * 16 + (lane & 15);
    const int d0 = h * 32 + (lane >> 4) * 8;
    const float* src = cb + ((size_t)q * KS + cw) * DIM + d0;
    f16x8 v;
#pragma unroll
    for (int j = 0; j < 8; ++j) {
        float c = src[j];
        _Float16 hi = (_Float16)c;
        v[j] = (l == 0) ? hi : (_Float16)((c - (float)hi) * RSCALE);
    }
    const int c = slot >> 4, w = slot & 15;
    *(f16x8*)(G + (size_t)c * 8320 + w * 512 + lane * 8) = v;
}

// ---- pre-pass 2: dc2 seeds written straight into each chunk's tail ----
__global__ void dc2_kernel(const float* __restrict__ cb, float* __restrict__ Gf) {
    int i = blockIdx.x * blockDim.x + threadIdx.x;
    if (i < QS * KS) {
        const float* c = cb + (size_t)i * DIM;
        float s = 0.f;
#pragma unroll
        for (int d = 0; d < DIM; ++d) s = fmaf(c[d], c[d], s);
        const int q = i >> 10, k = i & 1023;
        const int ch = q * 16 + (k >> 6), j = k & 63;
        Gf[(size_t)ch * 4160 + 4096 + j] = -1024.0f * s;
    }
}

#define CHUNK_B   16640     // bytes per chunk (16KB frags + 256B dc2)
#define CHUNK_H   8320      // _Float16 elements per chunk
#define DC2_OFF_H 8192      // half-offset of dc2 region (byte 16384)

__global__ __launch_bounds__(256, 4)
void rvq_mfma_kernel(const float* __restrict__ x,
                     const float* __restrict__ cbf,
                     const _Float16* __restrict__ F,
                     float* __restrict__ out) {
    __shared__ __attribute__((aligned(16))) _Float16 smem[2 * CHUNK_H]; // 33.3 KB

    const int tid  = threadIdx.x;
    const int wave = tid >> 6;
    const int lane = tid & 63;
    const int quad = lane >> 4;
    const int m    = lane & 15;
    const int quad4 = quad * 4;

    const int tokenBase = blockIdx.x * 128 + wave * 32;
    const int tokA = tokenBase + m, tokB = tokenBase + 16 + m;

    // token limbs (B-frag layout): th = hi, tl = 2048*(r-hi), ts = 2048*hi
    f16x8 thA0, thA1, tlA0, tlA1, tsA0, tsA1;
    f16x8 thB0, thB1, tlB0, tlB1, tsB0, tsB1;
    {
        const float* xa = x + (size_t)tokA * DIM + quad * 8;
        const float* xb = x + (size_t)tokB * DIM + quad * 8;
        f32x4 a0 = __builtin_nontemporal_load((const f32x4*)(xa));
        f32x4 a1 = __builtin_nontemporal_load((const f32x4*)(xa + 4));
        f32x4 a2 = __builtin_nontemporal_load((const f32x4*)(xa + 32));
        f32x4 a3 = __builtin_nontemporal_load((const f32x4*)(xa + 36));
        f32x4 b0 = __builtin_nontemporal_load((const f32x4*)(xb));
        f32x4 b1 = __builtin_nontemporal_load((const f32x4*)(xb + 4));
        f32x4 b2 = __builtin_nontemporal_load((const f32x4*)(xb + 32));
        f32x4 b3 = __builtin_nontemporal_load((const f32x4*)(xb + 36));
#pragma unroll
        for (int j = 0; j < 4; ++j) {
            SPLIT3(a0[j], thA0[j],   tlA0[j],   tsA0[j]);
            SPLIT3(a1[j], thA0[j+4], tlA0[j+4], tsA0[j+4]);
            SPLIT3(a2[j], thA1[j],   tlA1[j],   tsA1[j]);
            SPLIT3(a3[j], thA1[j+4], tlA1[j+4], tsA1[j+4]);
            SPLIT3(b0[j], thB0[j],   tlB0[j],   tsB0[j]);
            SPLIT3(b1[j], thB0[j+4], tlB0[j+4], tsB0[j+4]);
            SPLIT3(b2[j], thB1[j],   tlB1[j],   tsB1[j]);
            SPLIT3(b3[j], thB1[j+4], tlB1[j+4], tsB1[j+4]);
        }
    }

// stage one full chunk (frags + dc2 tail) of G into LDS buffer BUF.
// dest = wave-uniform base (+ lane*size implicit); global src is per-lane.
#define STAGE(GC, BUF) {                                                          \
        const char* _gs = (const char*)F + (size_t)(GC) * CHUNK_B                 \
                          + (wave << 10) + (lane << 4);                           \
        _Float16* _ld = smem + (BUF) * CHUNK_H + (wave << 9);                     \
        _Pragma("unroll")                                                         \
        for (int _j = 0; _j < 4; ++_j)                                            \
            __builtin_amdgcn_global_load_lds(                                     \
                (const __attribute__((address_space(1))) void*)(_gs + _j * 4096), \
                (__attribute__((address_space(3))) void*)(_ld + _j * 2048),       \
                16, 0, 0);                                                        \
        if (wave == 0) {                                                          \
            const char* _gd = (const char*)F + (size_t)(GC) * CHUNK_B + 16384     \
                              + (lane << 2);                                      \
            __builtin_amdgcn_global_load_lds(                                     \
                (const __attribute__((address_space(1))) void*)_gd,               \
                (__attribute__((address_space(3))) void*)(smem + (BUF) * CHUNK_H  \
                                                          + DC2_OFF_H),           \
                4, 0, 0);                                                         \
        }                                                                         \
    }

// One group: 2 chains of 6 MFMA; acc IS the scaled score, no VALU combine.
#define COMPUTE(CH0, CH1, CL0, CL1, CIV, G) {                                       \
        f32x4 accA = __builtin_amdgcn_mfma_f32_16x16x32_f16(CH0, tsA0, CIV, 0,0,0); \
        f32x4 accB = __builtin_amdgcn_mfma_f32_16x16x32_f16(CH0, tsB0, CIV, 0,0,0); \
        accA = __builtin_amdgcn_mfma_f32_16x16x32_f16(CH1, tsA1, accA, 0,0,0);      \
        accB = __builtin_amdgcn_mfma_f32_16x16x32_f16(CH1, tsB1, accB, 0,0,0);      \
        accA = __builtin_amdgcn_mfma_f32_16x16x32_f16(CL0, thA0, accA, 0,0,0);      \
        accB = __builtin_amdgcn_mfma_f32_16x16x32_f16(CL0, thB0, accB, 0,0,0);      \
        accA = __builtin_amdgcn_mfma_f32_16x16x32_f16(CL1, thA1, accA, 0,0,0);      \
        accB = __builtin_amdgcn_mfma_f32_16x16x32_f16(CL1, thB1, accB, 0,0,0);      \
        accA = __builtin_amdgcn_mfma_f32_16x16x32_f16(CH0, tlA0, accA, 0,0,0);      \
        accB = __builtin_amdgcn_mfma_f32_16x16x32_f16(CH0, tlB0, accB, 0,0,0);      \
        accA = __builtin_amdgcn_mfma_f32_16x16x32_f16(CH1, tlA1, accA, 0,0,0);      \
        accB = __builtin_amdgcn_mfma_f32_16x16x32_f16(CH1, tlB1, accB, 0,0,0);      \
        const int base = (G) * 16 + quad4;                                          \
        _Pragma("unroll")                                                           \
        for (int i = 0; i < 4; ++i) {                                               \
            if (accA[i] > bvA) { bvA = accA[i]; biA = base + i; }                   \
            if (accB[i] > bvB) { bvB = accB[i]; biB = base + i; }                   \
        }                                                                           \
    }

    // prologue: stage chunk 0 of stage 0
    STAGE(0, 0);
    __syncthreads();
    int cur = 0;

    for (int q = 0; q < QS; ++q) {
        const float* cfq = cbf + (size_t)q * KS * DIM;

        float bvA = -INFINITY, bvB = -INFINITY;
        int   biA = 0,         biB = 0;

        for (int ch = 0; ch < 16; ++ch) {
            const int gc = (q << 4) | ch;
            if (gc + 1 < 128) STAGE(gc + 1, cur ^ 1);   // prefetch next chunk

            const _Float16* L   = smem + cur * CHUNK_H + lane * 8;
            const float*    dcL = (const float*)(smem + cur * CHUNK_H + DC2_OFF_H);
            const int gbase = ch * 4;

            // dc2 seeds: 4 ds_reads up front (broadcast within quad, no conflict)
            f32x4 ci0 = *(const f32x4*)(dcL +  0 + quad4);
            f32x4 ci1 = *(const f32x4*)(dcL + 16 + quad4);
            f32x4 ci2 = *(const f32x4*)(dcL + 32 + quad4);
            f32x4 ci3 = *(const f32x4*)(dcL + 48 + quad4);

            // register double-buffer over the chunk's 4 groups (ds_read_b128)
            f16x8 c0h0 = *(const f16x8*)(L);
            f16x8 c0h1 = *(const f16x8*)(L + 512);
            f16x8 c0l0 = *(const f16x8*)(L + 1024);
            f16x8 c0l1 = *(const f16x8*)(L + 1536);

            f16x8 c1h0 = *(const f16x8*)(L + 2048);
            f16x8 c1h1 = *(const f16x8*)(L + 2560);
            f16x8 c1l0 = *(const f16x8*)(L + 3072);
            f16x8 c1l1 = *(const f16x8*)(L + 3584);

            COMPUTE(c0h0, c0h1, c0l0, c0l1, ci0, gbase + 0);

            c0h0 = *(const f16x8*)(L + 4096);
            c0h1 = *(const f16x8*)(L + 4608);
            c0l0 = *(const f16x8*)(L + 5120);
            c0l1 = *(const f16x8*)(L + 5632);

            COMPUTE(c1h0, c1h1, c1l0, c1l1, ci1, gbase + 1);

            c1h0 = *(const f16x8*)(L + 6144);
            c1h1 = *(const f16x8*)(L + 6656);
            c1l0 = *(const f16x8*)(L + 7168);
            c1l1 = *(const f16x8*)(L + 7680);

            COMPUTE(c0h0, c0h1, c0l0, c0l1, ci2, gbase + 2);
            COMPUTE(c1h0, c1h1, c1l0, c1l1, ci3, gbase + 3);

            // barrier doubles as vmcnt(0)/lgkmcnt(0) drain: staged chunk gc+1 is
            // now resident+visible, and all waves are done reading buffer cur.
            __syncthreads();
            cur ^= 1;
        }

        // reduce over the 4 quad-lanes holding the same token (disjoint codewords):
        // 2 shuffle steps. Tie-break: lowest index, matching jnp.argmin.
#pragma unroll
        for (int mask = 16; mask <= 32; mask <<= 1) {
            float ovA = __shfl_xor(bvA, mask, 64);
            int   oiA = __shfl_xor(biA, mask, 64);
            if (ovA > bvA || (ovA == bvA && oiA < biA)) { bvA = ovA; biA = oiA; }
            float ovB = __shfl_xor(bvB, mask, 64);
            int   oiB = __shfl_xor(biB, mask, 64);
            if (ovB > bvB || (ovB == bvB && oiB < biB)) { bvB = ovB; biB = oiB; }
        }

        // indices straight to global (every lane already has its token's winner)
        if (quad == 0)      out[(size_t)N_TOK * DIM + (size_t)tokA * QS + q] = (float)biA;
        else if (quad == 1) out[(size_t)N_TOK * DIM + (size_t)tokB * QS + q] = (float)biB;

        // residual update: reconstruct r from limbs, subtract fp32 codeword, re-split
        float ls = 0.f;
        {
            const float* cp = cfq + (size_t)biA * DIM + quad * 8;
            f32x4 c0 = *(const f32x4*)(cp);
            f32x4 c1 = *(const f32x4*)(cp + 4);
            f32x4 c2 = *(const f32x4*)(cp + 32);
            f32x4 c3 = *(const f32x4*)(cp + 36);
#pragma unroll
            for (int j = 0; j < 4; ++j) {
                float v0 = fmaf(RISCALE, (float)tlA0[j],   (float)thA0[j])   - c0[j];
                float v1 = fmaf(RISCALE, (float)tlA0[j+4], (float)thA0[j+4]) - c1[j];
                float v2 = fmaf(RISCALE, (float)tlA1[j],   (float)thA1[j])   - c2[j];
                float v3 = fmaf(RISCALE, (float)tlA1[j+4], (float)thA1[j+4]) - c3[j];
                ls = fmaf(v0, v0, ls); ls = fmaf(v1, v1, ls);
                ls = fmaf(v2, v2, ls); ls = fmaf(v3, v3, ls);
                SPLIT3(v0, thA0[j],   tlA0[j],   tsA0[j]);
                SPLIT3(v1, thA0[j+4], tlA0[j+4], tsA0[j+4]);
                SPLIT3(v2, thA1[j],   tlA1[j],   tsA1[j]);
                SPLIT3(v3, thA1[j+4], tlA1[j+4], tsA1[j+4]);
            }
        }
        {
            const float* cp = cfq + (size_t)biB * DIM + quad * 8;
            f32x4 c0 = *(const f32x4*)(cp);
            f32x4 c1 = *(const f32x4*)(cp + 4);
            f32x4 c2 = *(const f32x4*)(cp + 32);
            f32x4 c3 = *(const f32x4*)(cp + 36);
#pragma unroll
            for (int j = 0; j < 4; ++j) {
                float v0 = fmaf(RISCALE, (float)tlB0[j],   (float)thB0[j])   - c0[j];
                float v1 = fmaf(RISCALE, (float)tlB0[j+4], (float)thB0[j+4]) - c1[j];
                float v2 = fmaf(RISCALE, (float)tlB1[j],   (float)thB1[j])   - c2[j];
                float v3 = fmaf(RISCALE, (float)tlB1[j+4], (float)thB1[j+4]) - c3[j];
                ls = fmaf(v0, v0, ls); ls = fmaf(v1, v1, ls);
                ls = fmaf(v2, v2, ls); ls = fmaf(v3, v3, ls);
                SPLIT3(v0, thB0[j],   tlB0[j],   tsB0[j]);
                SPLIT3(v1, thB0[j+4], tlB0[j+4], tsB0[j+4]);
                SPLIT3(v2, thB1[j],   tlB1[j],   tsB1[j]);
                SPLIT3(v3, thB1[j+4], tlB1[j+4], tsB1[j+4]);
            }
        }
#pragma unroll
        for (int mask = 1; mask <= 32; mask <<= 1) ls += __shfl_xor(ls, mask, 64);
        if (lane == 0)
            atomicAdd(out + (size_t)N_TOK * DIM + (size_t)N_TOK * QS + q,
                      ls * (1.0f / ((float)N_TOK * (float)DIM)));
    }

    // xq = x - r_final (reconstruct final residual from limbs)
    {
        const size_t ra = (size_t)tokA * DIM + quad * 8;
        const size_t rb = (size_t)tokB * DIM + quad * 8;
        f32x4 a0 = __builtin_nontemporal_load((const f32x4*)(x + ra));
        f32x4 a1 = __builtin_nontemporal_load((const f32x4*)(x + ra + 4));
        f32x4 a2 = __builtin_nontemporal_load((const f32x4*)(x + ra + 32));
        f32x4 a3 = __builtin_nontemporal_load((const f32x4*)(x + ra + 36));
        f32x4 b0 = __builtin_nontemporal_load((const f32x4*)(x + rb));
        f32x4 b1 = __builtin_nontemporal_load((const f32x4*)(x + rb + 4));
        f32x4 b2 = __builtin_nontemporal_load((const f32x4*)(x + rb + 32));
        f32x4 b3 = __builtin_nontemporal_load((const f32x4*)(x + rb + 36));
#pragma unroll
        for (int j = 0; j < 4; ++j) {
            a0[j] -= fmaf(RISCALE, (float)tlA0[j],   (float)thA0[j]);
            a1[j] -= fmaf(RISCALE, (float)tlA0[j+4], (float)thA0[j+4]);
            a2[j] -= fmaf(RISCALE, (float)tlA1[j],   (float)thA1[j]);
            a3[j] -= fmaf(RISCALE, (float)tlA1[j+4], (float)thA1[j+4]);
            b0[j] -= fmaf(RISCALE, (float)tlB0[j],   (float)thB0[j]);
            b1[j] -= fmaf(RISCALE, (float)tlB0[j+4], (float)thB0[j+4]);
            b2[j] -= fmaf(RISCALE, (float)tlB1[j],   (float)thB1[j]);
            b3[j] -= fmaf(RISCALE, (float)tlB1[j+4], (float)thB1[j+4]);
        }
        __builtin_nontemporal_store(a0, (f32x4*)(out + ra));
        __builtin_nontemporal_store(a1, (f32x4*)(out + ra + 4));
        __builtin_nontemporal_store(a2, (f32x4*)(out + ra + 32));
        __builtin_nontemporal_store(a3, (f32x4*)(out + ra + 36));
        __builtin_nontemporal_store(b0, (f32x4*)(out + rb));
        __builtin_nontemporal_store(b1, (f32x4*)(out + rb + 4));
        __builtin_nontemporal_store(b2, (f32x4*)(out + rb + 32));
        __builtin_nontemporal_store(b3, (f32x4*)(out + rb + 36));
    }
#undef COMPUTE
#undef STAGE
}

extern "C" void kernel_launch(void* const* d_in, const int* in_sizes, int n_in,
                              void* d_out, int out_size, void* d_ws, size_t ws_size,
                              hipStream_t stream) {
    const float* x   = (const float*)d_in[0];   // (N, D)
    const float* cb  = (const float*)d_in[1];   // (Q, K, D)
    float*       out = (float*)d_out;           // [xq | indices | losses]
    char*        ws  = (char*)d_ws;

    _Float16* G = (_Float16*)ws;   // 128 chunks x 16640 B = 2,129,920 B

    hipMemsetAsync(out + (size_t)N_TOK * DIM + (size_t)N_TOK * QS, 0,
                   QS * sizeof(float), stream);

    conv_kernel<<<512, 256, 0, stream>>>(cb, G);
    dc2_kernel<<<(QS * KS + 255) / 256, 256, 0, stream>>>(cb, (float*)ws);
    rvq_mfma_kernel<<<N_TOK / 128, 256, 0, stream>>>(x, cb, G, out);
}